// Round 3
// baseline (141.389 us; speedup 1.0000x reference)
//
#include <hip/hip_runtime.h>
#include <hip/hip_bf16.h>
#include <math.h>

#define NN 2048

typedef __bf16 bf16x8 __attribute__((ext_vector_type(8)));
typedef float  f32x4  __attribute__((ext_vector_type(4)));
typedef float  f32x2  __attribute__((ext_vector_type(2)));

union BF8 { unsigned u[4]; bf16x8 v; };

__device__ __forceinline__ f32x2 pk_fma(f32x2 a, f32x2 b, f32x2 c){
  f32x2 d;
  asm("v_pk_fma_f32 %0, %1, %2, %3" : "=v"(d) : "v"(a), "v"(b), "v"(c));
  return d;
}
__device__ __forceinline__ unsigned cvtpk(float lo, float hi){
  unsigned r;
  asm("v_cvt_pk_bf16_f32 %0, %1, %2" : "=v"(r) : "v"(lo), "v"(hi));
  return r;
}

// ---------------- encode + qkv(iter1) ----------------
__global__ void k_encqkv(const float* __restrict__ x, const float* __restrict__ comms,
    const float* __restrict__ Wenc, const float* __restrict__ benc,
    const float* __restrict__ Wq, const float* __restrict__ bq,
    const float* __restrict__ Wk, const float* __restrict__ bk,
    const float* __restrict__ Wv, const float* __restrict__ bv,
    float* __restrict__ h, float* __restrict__ q, float* __restrict__ kk,
    __bf16* __restrict__ vpk)
{
  int t = threadIdx.x, b = blockIdx.x;
  int r = t >> 5, c = t & 31;
  int row = b*8 + r;
  float acc = benc[c];
  #pragma unroll
  for (int d=0; d<8; ++d) acc = fmaf(x[row*8+d],     Wenc[d*32+c],     acc);
  #pragma unroll
  for (int d=0; d<8; ++d) acc = fmaf(comms[row*8+d], Wenc[(8+d)*32+c], acc);
  __shared__ float hs[8][32];
  hs[r][c] = acc;
  h[row*32+c] = acc;
  __syncthreads();
  float aq=bq[c], ak=bk[c], av=bv[c];
  #pragma unroll 8
  for (int d=0; d<32; ++d){
    float hv = hs[r][d];
    aq = fmaf(hv, Wq[d*32+c], aq);
    ak = fmaf(hv, Wk[d*32+c], ak);
    av = fmaf(hv, Wv[d*32+c], av);
  }
  q[row*32+c]=aq; kk[row*32+c]=ak;
  // v in PV-fragment layout: vpk[(j>>3)*256 + c*8 + (j&7)]
  vpk[b*256 + c*8 + r] = (__bf16)av;
}

// ---------------- pairwise-MLP logits: one 16x16 (i,j) tile per wave ----------------
__launch_bounds__(256)
__global__ void k_logits(const float* __restrict__ q, const float* __restrict__ kk,
    const float* __restrict__ adj, const float* __restrict__ dense,
    const float* __restrict__ W1, const float* __restrict__ b1,
    const float* __restrict__ W2, const float* __restrict__ b2,
    const float* __restrict__ W3, const float* __restrict__ b3,
    float* __restrict__ logits)
{
  int t = threadIdx.x;
  int wave = t >> 6;
  int l = t & 63;
  int lj = l & 15, g = l >> 4;
  int j0 = blockIdx.x * 64 + wave * 16;
  int i0 = blockIdx.y * 16;
  int c1b = 8*g;

  // dots = kk @ q^T on this 16x16 tile
  const f32x4* kp = (const f32x4*)(kk + (i0+lj)*32 + c1b);
  f32x4 k0 = kp[0], k1 = kp[1];
  const f32x4* qp = (const f32x4*)(q + (j0+lj)*32 + c1b);
  f32x4 q0 = qp[0], q1 = qp[1];
  bf16x8 af, bq8;
  #pragma unroll
  for (int e=0;e<4;++e){
    af[e] = (__bf16)k0[e];  af[4+e] = (__bf16)k1[e];
    bq8[e] = (__bf16)q0[e]; bq8[4+e] = (__bf16)q1[e];
  }
  f32x4 dacc = {0.f,0.f,0.f,0.f};
  dacc = __builtin_amdgcn_mfma_f32_16x16x32_bf16(af, bq8, dacc, 0, 0, 0);
  // dacc[r] = dots[i0+4g+r][j0+lj] -> stash in LDS for imm-offset broadcast reads
  __shared__ float sdots[4][16][16];
  #pragma unroll
  for (int r=0;r<4;++r) sdots[wave][4*g+r][lj] = dacc[r];

  // per-lane W1/b1 as channel-pairs (c1 = 8g .. 8g+7)
  f32x2 w10s[4], w11s[4], w12s[4], b1s[4];
  #pragma unroll
  for (int p=0;p<4;++p){
    w10s[p] = ((const f32x2*)(W1 + c1b))[p];
    w11s[p] = ((const f32x2*)(W1 + 32 + c1b))[p];
    w12s[p] = ((const f32x2*)(W1 + 64 + c1b))[p];
    b1s[p]  = ((const f32x2*)(b1 + c1b))[p];
  }
  // A-frags for swapped W2 MFMA: A = W2^T (m = c2 within half, k = c1)
  bf16x8 w2f0, w2f1;
  #pragma unroll
  for (int e=0;e<8;++e){
    w2f0[e] = (__bf16)W2[(c1b+e)*32 + lj];
    w2f1[e] = (__bf16)W2[(c1b+e)*32 + 16 + lj];
  }
  // b2 slices as MFMA C-in (rows c2 = 4g+r / 16+4g+r)
  f32x4 b2lo = *(const f32x4*)(b2 + 4*g);
  f32x4 b2hi = *(const f32x4*)(b2 + 16 + 4*g);
  // W3 pairs matching (a0[0..3], a1[0..3])
  f32x2 w3s0 = *(const f32x2*)(W3 + 4*g);
  f32x2 w3s1 = *(const f32x2*)(W3 + 4*g + 2);
  f32x2 w3s2 = *(const f32x2*)(W3 + 16 + 4*g);
  f32x2 w3s3 = *(const f32x2*)(W3 + 16 + 4*g + 2);
  float b3v = b3[0];

  float adjv[16], denv[16];
  #pragma unroll
  for (int m=0;m<16;++m){
    adjv[m] = adj  [(i0+m)*NN + j0 + lj];
    denv[m] = dense[(i0+m)*NN + j0 + lj];
  }

  #pragma unroll
  for (int m=0;m<16;++m){
    float d = sdots[wave][m][lj];          // same addr across g-groups: LDS broadcast
    f32x2 d2 = {d, d};
    f32x2 a2 = {adjv[m], adjv[m]};
    f32x2 e2 = {denv[m], denv[m]};
    // f1 = relu(feats @ W1 + b1): 4 channel-pairs, 3-deep pk_fma chains
    BF8 fr;
    #pragma unroll
    for (int p=0;p<4;++p){
      f32x2 f_ = pk_fma(d2, w10s[p], pk_fma(a2, w11s[p], pk_fma(e2, w12s[p], b1s[p])));
      fr.u[p] = cvtpk(fmaxf(f_.x, 0.f), fmaxf(f_.y, 0.f));
    }
    // f2 + b2 via MFMA C-in: D[c2][pair], lane holds pair lj, c2 = 4g+r / 16+4g+r
    f32x4 a0 = __builtin_amdgcn_mfma_f32_16x16x32_bf16(w2f0, fr.v, b2lo, 0,0,0);
    f32x4 a1 = __builtin_amdgcn_mfma_f32_16x16x32_bf16(w2f1, fr.v, b2hi, 0,0,0);
    // relu + W3 dot (packed pairs)
    f32x2 p0 = {fmaxf(a0[0],0.f), fmaxf(a0[1],0.f)};
    f32x2 p1 = {fmaxf(a0[2],0.f), fmaxf(a0[3],0.f)};
    f32x2 p2 = {fmaxf(a1[0],0.f), fmaxf(a1[1],0.f)};
    f32x2 p3 = {fmaxf(a1[2],0.f), fmaxf(a1[3],0.f)};
    f32x2 z2 = {0.f, 0.f};
    f32x2 acc2 = pk_fma(p0, w3s0, pk_fma(p1, w3s1, pk_fma(p2, w3s2, pk_fma(p3, w3s3, z2))));
    float tl = acc2.x + acc2.y;
    tl += __shfl_xor(tl, 16, 64);
    tl += __shfl_xor(tl, 32, 64);
    tl += b3v;
    if (g == 0) logits[(i0+m)*NN + j0 + lj] = tl;
  }
}

// ---------------- softmax + focus@v + residual (+ fused qkv-next or decode) ----------------
template<int LAST>
__launch_bounds__(256)
__global__ void k_pv(const float* __restrict__ logits,
    const __bf16* __restrict__ vpk, const float* __restrict__ h_in,
    float* __restrict__ h_out,
    const float* __restrict__ Wq, const float* __restrict__ bq,
    const float* __restrict__ Wk, const float* __restrict__ bk,
    const float* __restrict__ Wv, const float* __restrict__ bv,
    float* __restrict__ qn, float* __restrict__ kn, __bf16* __restrict__ vpkn,
    const float* __restrict__ Wdec, const float* __restrict__ bdec,
    const float* __restrict__ mask, float* __restrict__ out)
{
  int t = threadIdx.x;
  int w = t >> 6;
  int l = t & 63;
  int li = l & 15, g = l >> 4;
  int i0 = blockIdx.x * 16;
  int jw = w * 512;
  const float* lrow = logits + (i0+li)*NN + jw + 8*g;

  // pre-pass: exact row max
  f32x4 mx4 = {-INFINITY,-INFINITY,-INFINITY,-INFINITY};
  for (int s=0; s<16; ++s){
    f32x4 p0 = *(const f32x4*)(lrow + s*32);
    f32x4 p1 = *(const f32x4*)(lrow + s*32 + 4);
    #pragma unroll
    for (int e=0;e<4;++e){ mx4[e] = fmaxf(mx4[e], p0[e]); mx4[e] = fmaxf(mx4[e], p1[e]); }
  }
  float mxl = fmaxf(fmaxf(mx4[0],mx4[1]), fmaxf(mx4[2],mx4[3]));
  mxl = fmaxf(mxl, __shfl_xor(mxl, 16, 64));
  mxl = fmaxf(mxl, __shfl_xor(mxl, 32, 64));
  __shared__ float Ms[4][16];
  if (l < 16) Ms[w][l] = mxl;
  __syncthreads();
  float Mrow = fmaxf(fmaxf(Ms[0][li],Ms[1][li]), fmaxf(Ms[2][li],Ms[3][li]));

  f32x4 acc0 = {0.f,0.f,0.f,0.f}, acc1 = {0.f,0.f,0.f,0.f};
  float Lp = 0.f;
  for (int s=0; s<16; ++s){
    int jb = jw + s*32 + 8*g;          // multiple of 8
    f32x4 p0 = *(const f32x4*)(lrow + s*32);
    f32x4 p1 = *(const f32x4*)(lrow + s*32 + 4);
    float ex[8];
    #pragma unroll
    for (int e=0;e<4;++e){ ex[e] = __expf(p0[e] - Mrow); ex[4+e] = __expf(p1[e] - Mrow); }
    BF8 pfr;
    #pragma unroll
    for (int p=0;p<4;++p) pfr.u[p] = cvtpk(ex[2*p], ex[2*p+1]);
    Lp += ((ex[0]+ex[1])+(ex[2]+ex[3])) + ((ex[4]+ex[5])+(ex[6]+ex[7]));
    int base = (jb >> 3) * 256;
    bf16x8 vf0 = *(const bf16x8*)(vpk + base + li*8);
    bf16x8 vf1 = *(const bf16x8*)(vpk + base + (16+li)*8);
    acc0 = __builtin_amdgcn_mfma_f32_16x16x32_bf16(pfr.v, vf0, acc0, 0,0,0);
    acc1 = __builtin_amdgcn_mfma_f32_16x16x32_bf16(pfr.v, vf1, acc1, 0,0,0);
  }
  Lp += __shfl_xor(Lp, 16, 64);
  Lp += __shfl_xor(Lp, 32, 64);
  __shared__ float accs[4][16][32];
  __shared__ float Ls[4][16];
  __shared__ float hsn[16][32];
  #pragma unroll
  for (int r=0;r<4;++r){
    accs[w][4*g+r][li]    = acc0[r];
    accs[w][4*g+r][16+li] = acc1[r];
  }
  if (l < 16) Ls[w][l] = Lp;
  __syncthreads();
  for (int o = t; o < 512; o += 256){
    int i = o >> 5, c = o & 31;
    float s4 = accs[0][i][c] + accs[1][i][c] + accs[2][i][c] + accs[3][i][c];
    float L4 = Ls[0][i] + Ls[1][i] + Ls[2][i] + Ls[3][i];
    float hnew = h_in[(i0+i)*32 + c] + s4 / L4;
    hsn[i][c] = hnew;
    if (!LAST) h_out[(i0+i)*32+c] = hnew;
  }
  __syncthreads();
  if (!LAST){
    for (int o = t; o < 512; o += 256){
      int i = o >> 5, c = o & 31;
      float aq = bq[c], ak = bk[c], av = bv[c];
      #pragma unroll 8
      for (int d=0; d<32; ++d){
        float hv = hsn[i][d];
        aq = fmaf(hv, Wq[d*32+c], aq);
        ak = fmaf(hv, Wk[d*32+c], ak);
        av = fmaf(hv, Wv[d*32+c], av);
      }
      int row = i0 + i;
      qn[row*32+c] = aq; kn[row*32+c] = ak;
      vpkn[(row>>3)*256 + c*8 + (row&7)] = (__bf16)av;
    }
  } else {
    __shared__ float red[16][16];
    int ii = t >> 4, cs = t & 15;
    float part = hsn[ii][2*cs]*Wdec[2*cs] + hsn[ii][2*cs+1]*Wdec[2*cs+1];
    red[ii][cs] = part;
    __syncthreads();
    if (t < 16){
      float sacc = 0.f;
      #pragma unroll
      for (int e=0;e<16;++e) sacc += red[t][e];
      float o = sacc + bdec[0];
      float mk = mask[i0+t];
      out[i0+t] = o + (mk == 0.f ? -INFINITY : 0.f);
    }
  }
}

extern "C" void kernel_launch(void* const* d_in, const int* in_sizes, int n_in,
                              void* d_out, int out_size, void* d_ws, size_t ws_size,
                              hipStream_t stream)
{
  const float* x     = (const float*)d_in[0];
  const float* comms = (const float*)d_in[1];
  const float* adj   = (const float*)d_in[2];
  const float* dense = (const float*)d_in[3];
  const float* mask  = (const float*)d_in[4];
  const float* Wenc  = (const float*)d_in[5];
  const float* benc  = (const float*)d_in[6];
  const float* Wq    = (const float*)d_in[7];
  const float* bq    = (const float*)d_in[8];
  const float* Wk    = (const float*)d_in[9];
  const float* bk    = (const float*)d_in[10];
  const float* Wv    = (const float*)d_in[11];
  const float* bv    = (const float*)d_in[12];
  const float* W1    = (const float*)d_in[13];
  const float* b1    = (const float*)d_in[14];
  const float* W2    = (const float*)d_in[15];
  const float* b2    = (const float*)d_in[16];
  const float* W3    = (const float*)d_in[17];
  const float* b3    = (const float*)d_in[18];
  const float* Wdec  = (const float*)d_in[19];
  const float* bdec  = (const float*)d_in[20];
  float* out = (float*)d_out;

  float* logits = (float*)d_ws;
  float* h1 = logits + (size_t)NN*NN;
  float* h2 = h1 + NN*32;
  float* q1 = h2 + NN*32;
  float* k1 = q1 + NN*32;
  float* q2 = k1 + NN*32;
  float* k2 = q2 + NN*32;
  __bf16* vpk1 = (__bf16*)(k2 + NN*32);
  __bf16* vpk2 = vpk1 + (size_t)NN*32;

  k_encqkv<<<256, 256, 0, stream>>>(x, comms, Wenc, benc, Wq,bq,Wk,bk,Wv,bv,
                                    h1, q1, k1, vpk1);
  dim3 gl(32, 128);
  k_logits<<<gl, 256, 0, stream>>>(q1, k1, adj, dense, W1,b1,W2,b2,W3,b3, logits);
  k_pv<0><<<128, 256, 0, stream>>>(logits, vpk1, h1, h2,
                                   Wq,bq,Wk,bk,Wv,bv, q2,k2,vpk2,
                                   nullptr, nullptr, nullptr, nullptr);
  k_logits<<<gl, 256, 0, stream>>>(q2, k2, adj, dense, W1,b1,W2,b2,W3,b3, logits);
  k_pv<1><<<128, 256, 0, stream>>>(logits, vpk2, h2, nullptr,
                                   nullptr,nullptr,nullptr,nullptr,nullptr,nullptr,
                                   nullptr,nullptr,nullptr,
                                   Wdec, bdec, mask, out);
}

// Round 4
// 129.595 us; speedup vs baseline: 1.0910x; 1.0910x over previous
//
#include <hip/hip_runtime.h>
#include <hip/hip_bf16.h>
#include <math.h>

#define NN 2048

typedef __bf16 bf16x8 __attribute__((ext_vector_type(8)));
typedef float  f32x4  __attribute__((ext_vector_type(4)));
typedef float  f32x2  __attribute__((ext_vector_type(2)));

union BF8 { unsigned u[4]; bf16x8 v; };

__device__ __forceinline__ f32x2 pfma(f32x2 a, f32x2 b, f32x2 c){
  return __builtin_elementwise_fma(a, b, c);
}
__device__ __forceinline__ f32x2 pmax0(f32x2 a){
  f32x2 z = {0.f, 0.f};
  return __builtin_elementwise_max(a, z);
}
__device__ __forceinline__ unsigned cvtpk(float lo, float hi){
  unsigned r;
  asm("v_cvt_pk_bf16_f32 %0, %1, %2" : "=v"(r) : "v"(lo), "v"(hi));
  return r;
}

// ---------------- encode + qkv(iter1) ----------------
__global__ void k_encqkv(const float* __restrict__ x, const float* __restrict__ comms,
    const float* __restrict__ Wenc, const float* __restrict__ benc,
    const float* __restrict__ Wq, const float* __restrict__ bq,
    const float* __restrict__ Wk, const float* __restrict__ bk,
    const float* __restrict__ Wv, const float* __restrict__ bv,
    float* __restrict__ h, float* __restrict__ q, float* __restrict__ kk,
    __bf16* __restrict__ vpk)
{
  int t = threadIdx.x, b = blockIdx.x;
  int r = t >> 5, c = t & 31;
  int row = b*8 + r;
  float acc = benc[c];
  #pragma unroll
  for (int d=0; d<8; ++d) acc = fmaf(x[row*8+d],     Wenc[d*32+c],     acc);
  #pragma unroll
  for (int d=0; d<8; ++d) acc = fmaf(comms[row*8+d], Wenc[(8+d)*32+c], acc);
  __shared__ float hs[8][32];
  hs[r][c] = acc;
  h[row*32+c] = acc;
  __syncthreads();
  float aq=bq[c], ak=bk[c], av=bv[c];
  #pragma unroll 8
  for (int d=0; d<32; ++d){
    float hv = hs[r][d];
    aq = fmaf(hv, Wq[d*32+c], aq);
    ak = fmaf(hv, Wk[d*32+c], ak);
    av = fmaf(hv, Wv[d*32+c], av);
  }
  q[row*32+c]=aq; kk[row*32+c]=ak;
  // v in PV-fragment layout: vpk[(j>>3)*256 + c*8 + (j&7)]
  vpk[b*256 + c*8 + r] = (__bf16)av;
}

// ---------------- pairwise-MLP logits: one 16x16 (i,j) tile per wave ----------------
// Round-2 structure (shfl broadcast, no LDS) + b2-in-C fold + compiler-visible
// packed f32x2 math (v_pk_fma_f32 / v_pk_max_f32 selected by the backend).
__launch_bounds__(256)
__global__ void k_logits(const float* __restrict__ q, const float* __restrict__ kk,
    const float* __restrict__ adj, const float* __restrict__ dense,
    const float* __restrict__ W1, const float* __restrict__ b1,
    const float* __restrict__ W2, const float* __restrict__ b2,
    const float* __restrict__ W3, const float* __restrict__ b3,
    float* __restrict__ logits)
{
  int t = threadIdx.x;
  int wave = t >> 6;
  int l = t & 63;
  int lj = l & 15, g = l >> 4;
  int j0 = blockIdx.x * 64 + wave * 16;
  int i0 = blockIdx.y * 16;
  int c1b = 8*g;

  // dots = kk @ q^T on this 16x16 tile
  const f32x4* kp = (const f32x4*)(kk + (i0+lj)*32 + c1b);
  f32x4 k0 = kp[0], k1 = kp[1];
  const f32x4* qp = (const f32x4*)(q + (j0+lj)*32 + c1b);
  f32x4 q0 = qp[0], q1 = qp[1];
  bf16x8 af, bq8;
  #pragma unroll
  for (int e=0;e<4;++e){
    af[e] = (__bf16)k0[e];  af[4+e] = (__bf16)k1[e];
    bq8[e] = (__bf16)q0[e]; bq8[4+e] = (__bf16)q1[e];
  }
  f32x4 dacc = {0.f,0.f,0.f,0.f};
  dacc = __builtin_amdgcn_mfma_f32_16x16x32_bf16(af, bq8, dacc, 0, 0, 0);
  // dacc[r] = dots[i0+4g+r][j0+lj]

  // per-lane W1/b1 as channel-pairs (c1 = 8g .. 8g+7)
  f32x2 w10s[4], w11s[4], w12s[4], b1s[4];
  #pragma unroll
  for (int p=0;p<4;++p){
    w10s[p] = ((const f32x2*)(W1 + c1b))[p];
    w11s[p] = ((const f32x2*)(W1 + 32 + c1b))[p];
    w12s[p] = ((const f32x2*)(W1 + 64 + c1b))[p];
    b1s[p]  = ((const f32x2*)(b1 + c1b))[p];
  }
  // A-frags for swapped W2 MFMA: A = W2^T (m = c2 within half, k = c1)
  bf16x8 w2f0, w2f1;
  #pragma unroll
  for (int e=0;e<8;++e){
    w2f0[e] = (__bf16)W2[(c1b+e)*32 + lj];
    w2f1[e] = (__bf16)W2[(c1b+e)*32 + 16 + lj];
  }
  // b2 slices as MFMA C-in (rows c2 = 4g+r / 16+4g+r)
  f32x4 b2lo = *(const f32x4*)(b2 + 4*g);
  f32x4 b2hi = *(const f32x4*)(b2 + 16 + 4*g);
  // W3 pairs matching (a0[0..3], a1[0..3])
  f32x2 w3s0 = *(const f32x2*)(W3 + 4*g);
  f32x2 w3s1 = *(const f32x2*)(W3 + 4*g + 2);
  f32x2 w3s2 = *(const f32x2*)(W3 + 16 + 4*g);
  f32x2 w3s3 = *(const f32x2*)(W3 + 16 + 4*g + 2);
  float b3v = b3[0];

  float adjv[16], denv[16];
  #pragma unroll
  for (int m=0;m<16;++m){
    adjv[m] = adj  [(i0+m)*NN + j0 + lj];
    denv[m] = dense[(i0+m)*NN + j0 + lj];
  }

  #pragma unroll
  for (int m=0;m<16;++m){
    // broadcast dots[i0+m][j0+lj] to all 4 k-groups
    float d = __shfl(dacc[m & 3], ((m >> 2) << 4) + lj, 64);
    f32x2 d2 = {d, d};
    f32x2 a2 = {adjv[m], adjv[m]};
    f32x2 e2 = {denv[m], denv[m]};
    // f1 = relu(feats @ W1 + b1): 4 channel-pairs, packed
    BF8 fr;
    #pragma unroll
    for (int p=0;p<4;++p){
      f32x2 f_ = pmax0(pfma(d2, w10s[p], pfma(a2, w11s[p], pfma(e2, w12s[p], b1s[p]))));
      fr.v[2*p]   = (__bf16)f_.x;       // clang fuses to v_cvt_pk_bf16_f32
      fr.v[2*p+1] = (__bf16)f_.y;
    }
    // f2 + b2 via MFMA C-in: D[c2][pair], lane holds pair lj, c2 = 4g+r / 16+4g+r
    f32x4 a0 = __builtin_amdgcn_mfma_f32_16x16x32_bf16(w2f0, fr.v, b2lo, 0,0,0);
    f32x4 a1 = __builtin_amdgcn_mfma_f32_16x16x32_bf16(w2f1, fr.v, b2hi, 0,0,0);
    // relu + W3 dot, packed pairs
    f32x2 p0 = pmax0((f32x2){a0[0], a0[1]});
    f32x2 p1 = pmax0((f32x2){a0[2], a0[3]});
    f32x2 p2 = pmax0((f32x2){a1[0], a1[1]});
    f32x2 p3 = pmax0((f32x2){a1[2], a1[3]});
    f32x2 z2 = {0.f, 0.f};
    f32x2 acc2 = pfma(p0, w3s0, pfma(p1, w3s1, pfma(p2, w3s2, pfma(p3, w3s3, z2))));
    float tl = acc2.x + acc2.y;
    tl += __shfl_xor(tl, 16, 64);
    tl += __shfl_xor(tl, 32, 64);
    tl += b3v;
    if (g == 0) logits[(i0+m)*NN + j0 + lj] = tl;
  }
}

// ---------------- softmax + focus@v + residual (+ fused qkv-next or decode) ----------------
template<int LAST>
__launch_bounds__(256)
__global__ void k_pv(const float* __restrict__ logits,
    const __bf16* __restrict__ vpk, const float* __restrict__ h_in,
    float* __restrict__ h_out,
    const float* __restrict__ Wq, const float* __restrict__ bq,
    const float* __restrict__ Wk, const float* __restrict__ bk,
    const float* __restrict__ Wv, const float* __restrict__ bv,
    float* __restrict__ qn, float* __restrict__ kn, __bf16* __restrict__ vpkn,
    const float* __restrict__ Wdec, const float* __restrict__ bdec,
    const float* __restrict__ mask, float* __restrict__ out)
{
  int t = threadIdx.x;
  int w = t >> 6;
  int l = t & 63;
  int li = l & 15, g = l >> 4;
  int i0 = blockIdx.x * 16;
  int jw = w * 512;
  const float* lrow = logits + (i0+li)*NN + jw + 8*g;

  // pre-pass: exact row max
  f32x4 mx4 = {-INFINITY,-INFINITY,-INFINITY,-INFINITY};
  for (int s=0; s<16; ++s){
    f32x4 p0 = *(const f32x4*)(lrow + s*32);
    f32x4 p1 = *(const f32x4*)(lrow + s*32 + 4);
    #pragma unroll
    for (int e=0;e<4;++e){ mx4[e] = fmaxf(mx4[e], p0[e]); mx4[e] = fmaxf(mx4[e], p1[e]); }
  }
  float mxl = fmaxf(fmaxf(mx4[0],mx4[1]), fmaxf(mx4[2],mx4[3]));
  mxl = fmaxf(mxl, __shfl_xor(mxl, 16, 64));
  mxl = fmaxf(mxl, __shfl_xor(mxl, 32, 64));
  __shared__ float Ms[4][16];
  if (l < 16) Ms[w][l] = mxl;
  __syncthreads();
  float Mrow = fmaxf(fmaxf(Ms[0][li],Ms[1][li]), fmaxf(Ms[2][li],Ms[3][li]));

  f32x4 acc0 = {0.f,0.f,0.f,0.f}, acc1 = {0.f,0.f,0.f,0.f};
  float Lp = 0.f;
  for (int s=0; s<16; ++s){
    int jb = jw + s*32 + 8*g;          // multiple of 8
    f32x4 p0 = *(const f32x4*)(lrow + s*32);
    f32x4 p1 = *(const f32x4*)(lrow + s*32 + 4);
    float ex[8];
    #pragma unroll
    for (int e=0;e<4;++e){ ex[e] = __expf(p0[e] - Mrow); ex[4+e] = __expf(p1[e] - Mrow); }
    BF8 pfr;
    #pragma unroll
    for (int p=0;p<4;++p) pfr.u[p] = cvtpk(ex[2*p], ex[2*p+1]);
    Lp += ((ex[0]+ex[1])+(ex[2]+ex[3])) + ((ex[4]+ex[5])+(ex[6]+ex[7]));
    int base = (jb >> 3) * 256;
    bf16x8 vf0 = *(const bf16x8*)(vpk + base + li*8);
    bf16x8 vf1 = *(const bf16x8*)(vpk + base + (16+li)*8);
    acc0 = __builtin_amdgcn_mfma_f32_16x16x32_bf16(pfr.v, vf0, acc0, 0,0,0);
    acc1 = __builtin_amdgcn_mfma_f32_16x16x32_bf16(pfr.v, vf1, acc1, 0,0,0);
  }
  Lp += __shfl_xor(Lp, 16, 64);
  Lp += __shfl_xor(Lp, 32, 64);
  __shared__ float accs[4][16][32];
  __shared__ float Ls[4][16];
  __shared__ float hsn[16][32];
  #pragma unroll
  for (int r=0;r<4;++r){
    accs[w][4*g+r][li]    = acc0[r];
    accs[w][4*g+r][16+li] = acc1[r];
  }
  if (l < 16) Ls[w][l] = Lp;
  __syncthreads();
  for (int o = t; o < 512; o += 256){
    int i = o >> 5, c = o & 31;
    float s4 = accs[0][i][c] + accs[1][i][c] + accs[2][i][c] + accs[3][i][c];
    float L4 = Ls[0][i] + Ls[1][i] + Ls[2][i] + Ls[3][i];
    float hnew = h_in[(i0+i)*32 + c] + s4 / L4;
    hsn[i][c] = hnew;
    if (!LAST) h_out[(i0+i)*32+c] = hnew;
  }
  __syncthreads();
  if (!LAST){
    for (int o = t; o < 512; o += 256){
      int i = o >> 5, c = o & 31;
      float aq = bq[c], ak = bk[c], av = bv[c];
      #pragma unroll 8
      for (int d=0; d<32; ++d){
        float hv = hsn[i][d];
        aq = fmaf(hv, Wq[d*32+c], aq);
        ak = fmaf(hv, Wk[d*32+c], ak);
        av = fmaf(hv, Wv[d*32+c], av);
      }
      int row = i0 + i;
      qn[row*32+c] = aq; kn[row*32+c] = ak;
      vpkn[(row>>3)*256 + c*8 + (row&7)] = (__bf16)av;
    }
  } else {
    __shared__ float red[16][16];
    int ii = t >> 4, cs = t & 15;
    float part = hsn[ii][2*cs]*Wdec[2*cs] + hsn[ii][2*cs+1]*Wdec[2*cs+1];
    red[ii][cs] = part;
    __syncthreads();
    if (t < 16){
      float sacc = 0.f;
      #pragma unroll
      for (int e=0;e<16;++e) sacc += red[t][e];
      float o = sacc + bdec[0];
      float mk = mask[i0+t];
      out[i0+t] = o + (mk == 0.f ? -INFINITY : 0.f);
    }
  }
}

extern "C" void kernel_launch(void* const* d_in, const int* in_sizes, int n_in,
                              void* d_out, int out_size, void* d_ws, size_t ws_size,
                              hipStream_t stream)
{
  const float* x     = (const float*)d_in[0];
  const float* comms = (const float*)d_in[1];
  const float* adj   = (const float*)d_in[2];
  const float* dense = (const float*)d_in[3];
  const float* mask  = (const float*)d_in[4];
  const float* Wenc  = (const float*)d_in[5];
  const float* benc  = (const float*)d_in[6];
  const float* Wq    = (const float*)d_in[7];
  const float* bq    = (const float*)d_in[8];
  const float* Wk    = (const float*)d_in[9];
  const float* bk    = (const float*)d_in[10];
  const float* Wv    = (const float*)d_in[11];
  const float* bv    = (const float*)d_in[12];
  const float* W1    = (const float*)d_in[13];
  const float* b1    = (const float*)d_in[14];
  const float* W2    = (const float*)d_in[15];
  const float* b2    = (const float*)d_in[16];
  const float* W3    = (const float*)d_in[17];
  const float* b3    = (const float*)d_in[18];
  const float* Wdec  = (const float*)d_in[19];
  const float* bdec  = (const float*)d_in[20];
  float* out = (float*)d_out;

  float* logits = (float*)d_ws;
  float* h1 = logits + (size_t)NN*NN;
  float* h2 = h1 + NN*32;
  float* q1 = h2 + NN*32;
  float* k1 = q1 + NN*32;
  float* q2 = k1 + NN*32;
  float* k2 = q2 + NN*32;
  __bf16* vpk1 = (__bf16*)(k2 + NN*32);
  __bf16* vpk2 = vpk1 + (size_t)NN*32;

  k_encqkv<<<256, 256, 0, stream>>>(x, comms, Wenc, benc, Wq,bq,Wk,bk,Wv,bv,
                                    h1, q1, k1, vpk1);
  dim3 gl(32, 128);
  k_logits<<<gl, 256, 0, stream>>>(q1, k1, adj, dense, W1,b1,W2,b2,W3,b3, logits);
  k_pv<0><<<128, 256, 0, stream>>>(logits, vpk1, h1, h2,
                                   Wq,bq,Wk,bk,Wv,bv, q2,k2,vpk2,
                                   nullptr, nullptr, nullptr, nullptr);
  k_logits<<<gl, 256, 0, stream>>>(q2, k2, adj, dense, W1,b1,W2,b2,W3,b3, logits);
  k_pv<1><<<128, 256, 0, stream>>>(logits, vpk2, h2, nullptr,
                                   nullptr,nullptr,nullptr,nullptr,nullptr,nullptr,
                                   nullptr,nullptr,nullptr,
                                   Wdec, bdec, mask, out);
}

// Round 6
// 96.509 us; speedup vs baseline: 1.4650x; 1.3428x over previous
//
#include <hip/hip_runtime.h>
#include <hip/hip_bf16.h>
#include <hip/hip_fp16.h>
#include <math.h>

#define NN 2048

typedef _Float16 f16x8 __attribute__((ext_vector_type(8)));
typedef _Float16 h2    __attribute__((ext_vector_type(2)));
typedef float    f32x4 __attribute__((ext_vector_type(4)));

union H8 { h2 h[4]; f16x8 v; };

__device__ __forceinline__ h2 pkrtz(float a, float b){
  return __builtin_bit_cast(h2, __builtin_amdgcn_cvt_pkrtz(a, b));
}
__device__ __forceinline__ h2 hfma(h2 a, h2 b, h2 c){
  return __builtin_elementwise_fma(a, b, c);
}
__device__ __forceinline__ h2 hmax0(h2 a){
  h2 z = {(_Float16)0.f, (_Float16)0.f};
  return __builtin_elementwise_max(a, z);
}

// ---------------- encode + qkv(iter1) + f16 weight prep ----------------
__global__ void k_encqkv(const float* __restrict__ x, const float* __restrict__ comms,
    const float* __restrict__ Wenc, const float* __restrict__ benc,
    const float* __restrict__ Wq, const float* __restrict__ bq,
    const float* __restrict__ Wk, const float* __restrict__ bk,
    const float* __restrict__ Wv, const float* __restrict__ bv,
    const float* __restrict__ W1, const float* __restrict__ b1,
    const float* __restrict__ W2,
    float* __restrict__ h, _Float16* __restrict__ qh, _Float16* __restrict__ kh,
    _Float16* __restrict__ vpk,
    _Float16* __restrict__ W1h, _Float16* __restrict__ b1h, _Float16* __restrict__ W2t)
{
  int t = threadIdx.x, b = blockIdx.x;
  if (b == 0){
    // one-time f16 weight prep (rewritten every launch: deterministic)
    if (t < 96) W1h[t] = (_Float16)W1[t];
    if (t < 32) b1h[t] = (_Float16)b1[t];
    #pragma unroll
    for (int idx = t; idx < 1024; idx += 256){
      int c2 = idx >> 5, c1 = idx & 31;
      W2t[idx] = (_Float16)W2[c1*32 + c2];   // W2t[c2][c1] = W2[c1][c2]
    }
  }
  int r = t >> 5, c = t & 31;
  int row = b*8 + r;
  float acc = benc[c];
  #pragma unroll
  for (int d=0; d<8; ++d) acc = fmaf(x[row*8+d],     Wenc[d*32+c],     acc);
  #pragma unroll
  for (int d=0; d<8; ++d) acc = fmaf(comms[row*8+d], Wenc[(8+d)*32+c], acc);
  __shared__ float hs[8][32];
  hs[r][c] = acc;
  h[row*32+c] = acc;
  __syncthreads();
  float aq=bq[c], ak=bk[c], av=bv[c];
  #pragma unroll 8
  for (int d=0; d<32; ++d){
    float hv = hs[r][d];
    aq = fmaf(hv, Wq[d*32+c], aq);
    ak = fmaf(hv, Wk[d*32+c], ak);
    av = fmaf(hv, Wv[d*32+c], av);
  }
  qh[row*32+c] = (_Float16)aq;
  kh[row*32+c] = (_Float16)ak;
  // v in PV-fragment layout: vpk[(j>>3)*256 + c*8 + (j&7)]
  vpk[b*256 + c*8 + r] = (_Float16)av;
}

// ---------------- pairwise-MLP logits: one 16x16 (i,j) tile per wave ----------------
// f16 pipeline: pk_fma_f16 output IS the MFMA fragment; no per-m cvt chain.
__launch_bounds__(256)
__global__ void k_logits(const _Float16* __restrict__ qh, const _Float16* __restrict__ kh,
    const float* __restrict__ adj, const float* __restrict__ dense,
    const _Float16* __restrict__ W1h, const _Float16* __restrict__ b1h,
    const _Float16* __restrict__ W2t,
    const float* __restrict__ b2, const float* __restrict__ W3,
    const float* __restrict__ b3,
    float* __restrict__ logits)
{
  int t = threadIdx.x;
  int wave = t >> 6;
  int l = t & 63;
  int lj = l & 15, g = l >> 4;
  int j0 = blockIdx.x * 64 + wave * 16;
  int i0 = blockIdx.y * 16;
  int c1b = 8*g;

  // dots = kk @ q^T on this 16x16 tile (A = k-rows i, B[k][j] = q[j][k])
  f16x8 af = *(const f16x8*)(kh + (i0+lj)*32 + c1b);
  f16x8 bq = *(const f16x8*)(qh + (j0+lj)*32 + c1b);
  f32x4 dacc = {0.f,0.f,0.f,0.f};
  dacc = __builtin_amdgcn_mfma_f32_16x16x32_f16(af, bq, dacc, 0, 0, 0);
  // dacc[r] = dots[i0+4g+r][j0+lj]

  // per-lane W1/b1 as f16 channel-pairs (c1 = 8g..8g+7)
  h2 w10[4], w11[4], w12[4], b1v[4];
  #pragma unroll
  for (int p=0;p<4;++p){
    w10[p] = ((const h2*)(W1h      + c1b))[p];
    w11[p] = ((const h2*)(W1h + 32 + c1b))[p];
    w12[p] = ((const h2*)(W1h + 64 + c1b))[p];
    b1v[p] = ((const h2*)(b1h      + c1b))[p];
  }
  // A-frags for swapped W2 MFMA (A = W2^T): contiguous from pre-transposed W2t
  f16x8 w2f0 = *(const f16x8*)(W2t + lj*32 + c1b);
  f16x8 w2f1 = *(const f16x8*)(W2t + (16+lj)*32 + c1b);
  // b2 as MFMA C-in (rows c2 = 4g+r / 16+4g+r)
  f32x4 b2lo = *(const f32x4*)(b2 + 4*g);
  f32x4 b2hi = *(const f32x4*)(b2 + 16 + 4*g);
  f32x4 w3lo = *(const f32x4*)(W3 + 4*g);
  f32x4 w3hi = *(const f32x4*)(W3 + 16 + 4*g);
  float b3v = b3[0];

  // preload adj/dense as pre-splatted f16 pairs (1 VGPR per m per array)
  h2 adjh[16], denh[16];
  #pragma unroll
  for (int m=0;m<16;++m){
    float a_ = adj  [(i0+m)*NN + j0 + lj];
    float d_ = dense[(i0+m)*NN + j0 + lj];
    adjh[m] = pkrtz(a_, a_);
    denh[m] = pkrtz(d_, d_);
  }

  #pragma unroll
  for (int m=0;m<16;++m){
    // broadcast dots[i0+m][j0+lj] to all 4 k-groups
    float d = __shfl(dacc[m & 3], ((m >> 2) << 4) + lj, 64);
    h2 dh = pkrtz(d, d);
    // f1 = relu(feats @ W1 + b1): 4 f16 pairs; result IS the MFMA B-frag
    H8 fr;
    #pragma unroll
    for (int p=0;p<4;++p)
      fr.h[p] = hmax0(hfma(dh, w10[p], hfma(adjh[m], w11[p], hfma(denh[m], w12[p], b1v[p]))));
    // f2 + b2 via MFMA C-in: D[c2][pair], lane holds pair lj, c2 = 4g+r / 16+4g+r
    f32x4 a0 = __builtin_amdgcn_mfma_f32_16x16x32_f16(w2f0, fr.v, b2lo, 0,0,0);
    f32x4 a1 = __builtin_amdgcn_mfma_f32_16x16x32_f16(w2f1, fr.v, b2hi, 0,0,0);
    // relu + W3 dot: 2-accumulator scalar tree (keeps ILP)
    float s0 = fmaxf(a0[0],0.f)*w3lo[0];
    float s1 = fmaxf(a0[1],0.f)*w3lo[1];
    s0 = fmaf(fmaxf(a0[2],0.f), w3lo[2], s0);
    s1 = fmaf(fmaxf(a0[3],0.f), w3lo[3], s1);
    s0 = fmaf(fmaxf(a1[0],0.f), w3hi[0], s0);
    s1 = fmaf(fmaxf(a1[1],0.f), w3hi[1], s1);
    s0 = fmaf(fmaxf(a1[2],0.f), w3hi[2], s0);
    s1 = fmaf(fmaxf(a1[3],0.f), w3hi[3], s1);
    float tl = s0 + s1;
    tl += __shfl_xor(tl, 16, 64);
    tl += __shfl_xor(tl, 32, 64);
    tl += b3v;
    if (g == 0) logits[(i0+m)*NN + j0 + lj] = tl;
  }
}

// ---------------- softmax + focus@v + residual (+ fused qkv-next or decode) ----------------
template<int LAST>
__launch_bounds__(256)
__global__ void k_pv(const float* __restrict__ logits,
    const _Float16* __restrict__ vpk, const float* __restrict__ h_in,
    float* __restrict__ h_out,
    const float* __restrict__ Wq, const float* __restrict__ bq,
    const float* __restrict__ Wk, const float* __restrict__ bk,
    const float* __restrict__ Wv, const float* __restrict__ bv,
    _Float16* __restrict__ qn, _Float16* __restrict__ kn, _Float16* __restrict__ vpkn,
    const float* __restrict__ Wdec, const float* __restrict__ bdec,
    const float* __restrict__ mask, float* __restrict__ out)
{
  int t = threadIdx.x;
  int w = t >> 6;
  int l = t & 63;
  int li = l & 15, g = l >> 4;
  int i0 = blockIdx.x * 16;
  int jw = w * 512;
  const float* lrow = logits + (i0+li)*NN + jw + 8*g;

  // pre-pass: exact row max
  f32x4 mx4 = {-INFINITY,-INFINITY,-INFINITY,-INFINITY};
  for (int s=0; s<16; ++s){
    f32x4 p0 = *(const f32x4*)(lrow + s*32);
    f32x4 p1 = *(const f32x4*)(lrow + s*32 + 4);
    #pragma unroll
    for (int e=0;e<4;++e){ mx4[e] = fmaxf(mx4[e], p0[e]); mx4[e] = fmaxf(mx4[e], p1[e]); }
  }
  float mxl = fmaxf(fmaxf(mx4[0],mx4[1]), fmaxf(mx4[2],mx4[3]));
  mxl = fmaxf(mxl, __shfl_xor(mxl, 16, 64));
  mxl = fmaxf(mxl, __shfl_xor(mxl, 32, 64));
  __shared__ float Ms[4][16];
  if (l < 16) Ms[w][l] = mxl;
  __syncthreads();
  float Mrow = fmaxf(fmaxf(Ms[0][li],Ms[1][li]), fmaxf(Ms[2][li],Ms[3][li]));

  f32x4 acc0 = {0.f,0.f,0.f,0.f}, acc1 = {0.f,0.f,0.f,0.f};
  float Lp = 0.f;
  for (int s=0; s<16; ++s){
    int jb = jw + s*32 + 8*g;          // multiple of 8
    f32x4 p0 = *(const f32x4*)(lrow + s*32);
    f32x4 p1 = *(const f32x4*)(lrow + s*32 + 4);
    float ex[8];
    #pragma unroll
    for (int e=0;e<4;++e){ ex[e] = __expf(p0[e] - Mrow); ex[4+e] = __expf(p1[e] - Mrow); }
    H8 pfr;
    #pragma unroll
    for (int p=0;p<4;++p) pfr.h[p] = pkrtz(ex[2*p], ex[2*p+1]);
    Lp += ((ex[0]+ex[1])+(ex[2]+ex[3])) + ((ex[4]+ex[5])+(ex[6]+ex[7]));
    int base = (jb >> 3) * 256;
    f16x8 vf0 = *(const f16x8*)(vpk + base + li*8);
    f16x8 vf1 = *(const f16x8*)(vpk + base + (16+li)*8);
    acc0 = __builtin_amdgcn_mfma_f32_16x16x32_f16(pfr.v, vf0, acc0, 0,0,0);
    acc1 = __builtin_amdgcn_mfma_f32_16x16x32_f16(pfr.v, vf1, acc1, 0,0,0);
  }
  Lp += __shfl_xor(Lp, 16, 64);
  Lp += __shfl_xor(Lp, 32, 64);
  __shared__ float accs[4][16][32];
  __shared__ float Ls[4][16];
  __shared__ float hsn[16][32];
  #pragma unroll
  for (int r=0;r<4;++r){
    accs[w][4*g+r][li]    = acc0[r];
    accs[w][4*g+r][16+li] = acc1[r];
  }
  if (l < 16) Ls[w][l] = Lp;
  __syncthreads();
  for (int o = t; o < 512; o += 256){
    int i = o >> 5, c = o & 31;
    float s4 = accs[0][i][c] + accs[1][i][c] + accs[2][i][c] + accs[3][i][c];
    float L4 = Ls[0][i] + Ls[1][i] + Ls[2][i] + Ls[3][i];
    float hnew = h_in[(i0+i)*32 + c] + s4 / L4;
    hsn[i][c] = hnew;
    if (!LAST) h_out[(i0+i)*32+c] = hnew;
  }
  __syncthreads();
  if (!LAST){
    for (int o = t; o < 512; o += 256){
      int i = o >> 5, c = o & 31;
      float aq = bq[c], ak = bk[c], av = bv[c];
      #pragma unroll 8
      for (int d=0; d<32; ++d){
        float hv = hsn[i][d];
        aq = fmaf(hv, Wq[d*32+c], aq);
        ak = fmaf(hv, Wk[d*32+c], ak);
        av = fmaf(hv, Wv[d*32+c], av);
      }
      int row = i0 + i;
      qn[row*32+c] = (_Float16)aq;
      kn[row*32+c] = (_Float16)ak;
      vpkn[(row>>3)*256 + c*8 + (row&7)] = (_Float16)av;
    }
  } else {
    __shared__ float red[16][16];
    int ii = t >> 4, cs = t & 15;
    float part = hsn[ii][2*cs]*Wdec[2*cs] + hsn[ii][2*cs+1]*Wdec[2*cs+1];
    red[ii][cs] = part;
    __syncthreads();
    if (t < 16){
      float sacc = 0.f;
      #pragma unroll
      for (int e=0;e<16;++e) sacc += red[t][e];
      float o = sacc + bdec[0];
      float mk = mask[i0+t];
      out[i0+t] = o + (mk == 0.f ? -INFINITY : 0.f);
    }
  }
}

extern "C" void kernel_launch(void* const* d_in, const int* in_sizes, int n_in,
                              void* d_out, int out_size, void* d_ws, size_t ws_size,
                              hipStream_t stream)
{
  const float* x     = (const float*)d_in[0];
  const float* comms = (const float*)d_in[1];
  const float* adj   = (const float*)d_in[2];
  const float* dense = (const float*)d_in[3];
  const float* mask  = (const float*)d_in[4];
  const float* Wenc  = (const float*)d_in[5];
  const float* benc  = (const float*)d_in[6];
  const float* Wq    = (const float*)d_in[7];
  const float* bq    = (const float*)d_in[8];
  const float* Wk    = (const float*)d_in[9];
  const float* bk    = (const float*)d_in[10];
  const float* Wv    = (const float*)d_in[11];
  const float* bv    = (const float*)d_in[12];
  const float* W1    = (const float*)d_in[13];
  const float* b1    = (const float*)d_in[14];
  const float* W2    = (const float*)d_in[15];
  const float* b2    = (const float*)d_in[16];
  const float* W3    = (const float*)d_in[17];
  const float* b3    = (const float*)d_in[18];
  const float* Wdec  = (const float*)d_in[19];
  const float* bdec  = (const float*)d_in[20];
  float* out = (float*)d_out;

  float* logits = (float*)d_ws;
  float* h1 = logits + (size_t)NN*NN;
  float* h2 = h1 + NN*32;
  _Float16* qh1  = (_Float16*)(h2 + NN*32);
  _Float16* kh1  = qh1 + (size_t)NN*32;
  _Float16* qh2  = kh1 + (size_t)NN*32;
  _Float16* kh2  = qh2 + (size_t)NN*32;
  _Float16* vpk1 = kh2 + (size_t)NN*32;
  _Float16* vpk2 = vpk1 + (size_t)NN*32;
  _Float16* W1h  = vpk2 + (size_t)NN*32;  // 96
  _Float16* b1h  = W1h + 96;              // 32
  _Float16* W2t  = b1h + 32;              // 1024

  k_encqkv<<<256, 256, 0, stream>>>(x, comms, Wenc, benc, Wq,bq,Wk,bk,Wv,bv,
                                    W1, b1, W2,
                                    h1, qh1, kh1, vpk1, W1h, b1h, W2t);
  dim3 gl(32, 128);
  k_logits<<<gl, 256, 0, stream>>>(qh1, kh1, adj, dense, W1h, b1h, W2t,
                                   b2, W3, b3, logits);
  k_pv<0><<<128, 256, 0, stream>>>(logits, vpk1, h1, h2,
                                   Wq,bq,Wk,bk,Wv,bv, qh2,kh2,vpk2,
                                   nullptr, nullptr, nullptr, nullptr);
  k_logits<<<gl, 256, 0, stream>>>(qh2, kh2, adj, dense, W1h, b1h, W2t,
                                   b2, W3, b3, logits);
  k_pv<1><<<128, 256, 0, stream>>>(logits, vpk2, h2, nullptr,
                                   nullptr,nullptr,nullptr,nullptr,nullptr,nullptr,
                                   nullptr,nullptr,nullptr,
                                   Wdec, bdec, mask, out);
}